// Round 8
// baseline (1117.916 us; speedup 1.0000x reference)
//
#include <hip/hip_runtime.h>
#include <type_traits>
#include <utility>

typedef unsigned short u16;
typedef __attribute__((ext_vector_type(8))) short short8;
typedef __attribute__((ext_vector_type(8))) __bf16 bf16v8;
typedef __attribute__((ext_vector_type(4))) float f32x4;
typedef __attribute__((ext_vector_type(16))) float f32x16;

template <typename T, typename = void> struct mfma_ok : std::false_type {};
template <typename T>
struct mfma_ok<T, std::void_t<decltype(__builtin_amdgcn_mfma_f32_16x16x32_bf16(
    std::declval<T>(), std::declval<T>(), std::declval<f32x4>(), 0, 0, 0))>>
    : std::true_type {};
using frag8 = std::conditional_t<mfma_ok<bf16v8>::value, bf16v8, short8>;

#define MFMA16(a, b, c) __builtin_amdgcn_mfma_f32_16x16x32_bf16((a), (b), (c), 0, 0, 0)
#define MFMA32(a, b, c) __builtin_amdgcn_mfma_f32_32x32x16_bf16((a), (b), (c), 0, 0, 0)

__device__ __forceinline__ float bf2f(u16 u) {
  unsigned v = ((unsigned)u) << 16;
  return __builtin_bit_cast(float, v);
}
__device__ __forceinline__ u16 f2bf(float f) {
  unsigned u = __builtin_bit_cast(unsigned, f);
  u = (u + 0x7fffu + ((u >> 16) & 1u)) >> 16;
  return (u16)u;
}
__device__ __forceinline__ unsigned cvtpk_bf16(float lo, float hi) {
  unsigned r;
  asm("v_cvt_pk_bf16_f32 %0, %1, %2" : "=v"(r) : "v"(lo), "v"(hi));
  return r;
}
// async global->LDS, 16B per lane; lds ptr must be wave-uniform base (+lane*16 implicit)
__device__ __forceinline__ void gl16(const u16* g, u16* l) {
  __builtin_amdgcn_global_load_lds((__attribute__((address_space(1))) void*)(g),
                                   (__attribute__((address_space(3))) void*)(l), 16, 0, 0);
}
__device__ __forceinline__ void vmw8() { asm volatile("s_waitcnt vmcnt(8)" ::: "memory"); }
__device__ __forceinline__ void vmw0() { asm volatile("s_waitcnt vmcnt(0)" ::: "memory"); }
__device__ __forceinline__ void lgw0() { asm volatile("s_waitcnt lgkmcnt(0)" ::: "memory"); }

// ---------------------------------------------------------------- score
__global__ void k_score(const float* __restrict__ prob, const float* __restrict__ wfix,
                        float* __restrict__ scores) {
  const int b = blockIdx.x, tid = threadIdx.x;
  __shared__ float ent[64 * 64];
  __shared__ float wf[64];
  if (tid < 64) wf[tid] = wfix[tid];
  const float* pb = prob + (size_t)b * 4 * 4096;
  for (int p = tid; p < 4096; p += 256) {
    float e = 0.f;
#pragma unroll
    for (int ch = 0; ch < 4; ++ch) {
      float v = pb[ch * 4096 + p];
      e -= v * log2f(v + 1e-10f);
    }
    ent[p] = e;
  }
  __syncthreads();
  if (tid < 225) {
    int wy = tid / 15, wx = tid % 15;
    float s = 0.f;
    for (int a = 0; a < 8; ++a)
      for (int c = 0; c < 8; ++c)
        s += ent[(wy * 4 + a) * 64 + wx * 4 + c] * wf[a * 8 + c];
    scores[b * 225 + tid] = s * (1.0f / 64.0f);
  }
}

// ---------------------------------------------------------------- nms
__device__ __forceinline__ float iou_pair(int wa, int wb) {
  float x1a = (float)((wa % 15) * 8), y1a = (float)((wa / 15) * 8);
  float x1b = (float)((wb % 15) * 8), y1b = (float)((wb / 15) * 8);
  float iw = fminf(x1a, x1b) + 15.f - fmaxf(x1a, x1b);
  float ih = fminf(y1a, y1b) + 15.f - fmaxf(y1a, y1b);
  iw = fmaxf(iw, 0.f);
  ih = fmaxf(ih, 0.f);
  float inter = iw * ih;
  return inter / (450.f - inter);
}

__global__ void k_nms(const float* __restrict__ scores, int* __restrict__ sel,
                      int* __restrict__ kept, float* __restrict__ mult) {
  const int b = blockIdx.x, t = threadIdx.x;
  __shared__ float s[225];
  __shared__ int order[225];
  __shared__ unsigned char supp[225];
  __shared__ int idx44[44];
  __shared__ int ks[225];
  __shared__ float ml[225];
  if (t < 225) s[t] = scores[b * 225 + t];
  __syncthreads();
  if (t < 225) {
    float st = s[t];
    int r = 0;
    for (int j = 0; j < 225; ++j) {
      float sj = s[j];
      r += (sj > st) || (sj == st && j < t);
    }
    order[r] = t;
    supp[t] = 0;
    ks[t] = -1;
    ml[t] = 0.f;
  }
  __syncthreads();
  for (int i = 0; i < 224; ++i) {
    if (t > i && t < 225 && !supp[i]) {
      if (iou_pair(order[i], order[t]) > 0.2f) supp[t] = 1;
    }
    __syncthreads();
  }
  if (t == 0) {
    int k = 0;
    for (int i = 0; i < 225 && k < 44; ++i)
      if (!supp[i]) idx44[k++] = order[i];
    while (k < 44) idx44[k++] = order[224];
    for (int k2 = 0; k2 < 44; ++k2) {
      int w = idx44[k2];
      if (ks[w] < 0) ks[w] = k2;
      ml[w] += 1.f;
    }
  }
  __syncthreads();
  if (t < 225) {
    kept[b * 225 + t] = ks[t];
    mult[b * 225 + t] = ml[t];
  }
  if (t < 44) sel[b * 44 + t] = idx44[t];
}

// ---------------------------------------------------------------- weight cast
__global__ void k_castw(const float* __restrict__ Wq, const float* __restrict__ Wo,
                        u16* __restrict__ wqb, u16* __restrict__ wob) {
  int idx = blockIdx.x * 256 + threadIdx.x;
  if (idx < 786432) wqb[idx] = f2bf(Wq[idx]);
  int i2 = idx - 786432;
  if (i2 >= 0 && i2 < 262144) wob[i2] = f2bf(Wo[i2]);
}

// ---------------------------------------------------------------- gather + bilinear (direct 4-tap)
__global__ __launch_bounds__(256) void k_gather(const float* __restrict__ x,
                                                const int* __restrict__ sel,
                                                u16* __restrict__ xi) {
  const size_t idx = (size_t)blockIdx.x * 256 + threadIdx.x;
  const int dc = (int)(idx & 63);
  const int pq = (int)((idx >> 6) & 255);
  const int g = (int)(idx >> 14);
  const int b = g / 44;
  const int w = sel[g];
  const int sy = (w / 15) * 8, sx = (w % 15) * 8;
  const int p = pq >> 4, q = pq & 15;
  float rp = ((float)p + 0.5f) * 0.9375f;
  int i0 = (int)rp;
  float fp = rp - (float)i0;
  float rq = ((float)q + 0.5f) * 0.9375f;
  int j0 = (int)rq;
  float fq = rq - (float)j0;
  const float w00 = (1.f - fp) * (1.f - fq), w01 = (1.f - fp) * fq;
  const float w10 = fp * (1.f - fq), w11 = fp * fq;
  const float* xb = x + ((size_t)b * 16384 + (size_t)(sy + i0) * 128 + sx + j0) * 512 + dc * 8;
  const float4* t00 = (const float4*)xb;
  const float4* t01 = (const float4*)(xb + 512);
  const float4* t10 = (const float4*)(xb + 512 * 128);
  const float4* t11 = (const float4*)(xb + 512 * 129);
  float acc[8];
#pragma unroll
  for (int h = 0; h < 2; ++h) {
    float4 a = t00[h], bb = t01[h], c = t10[h], d = t11[h];
    acc[h * 4 + 0] = w00 * a.x + w01 * bb.x + w10 * c.x + w11 * d.x;
    acc[h * 4 + 1] = w00 * a.y + w01 * bb.y + w10 * c.y + w11 * d.y;
    acc[h * 4 + 2] = w00 * a.z + w01 * bb.z + w10 * c.z + w11 * d.z;
    acc[h * 4 + 3] = w00 * a.w + w01 * bb.w + w10 * c.w + w11 * d.w;
  }
  short8 o;
#pragma unroll
  for (int e = 0; e < 8; ++e) o[e] = (short)f2bf(acc[e]);
  *(short8*)&xi[((size_t)g * 256 + pq) * 512 + dc * 8] = o;
}

// ---------------------------------------------------------------- GEMM 256x256, BK=64, 8 waves
// Counted-vmcnt dbuf + T2 XOR swizzle + per-mh fragment hoist + STAGE under compute.
template <int BIAS>
__global__ __launch_bounds__(512, 2) void k_gemm256(const u16* __restrict__ A,
                                                    const u16* __restrict__ B, u16* __restrict__ C,
                                                    const float* __restrict__ bias, int M, int N,
                                                    int K, int nbn) {
  __shared__ u16 sA[2][256 * 64];
  __shared__ u16 sB[2][256 * 64];
  const int tid = threadIdx.x, lane = tid & 63, wv = tid >> 6;
  const int f = blockIdx.x;
  const int q8 = gridDim.x >> 3;
  const int wg = (f & 7) * q8 + (f >> 3);
  const int bm = wg / nbn, bn = wg % nbn;
  const int wm = (wv >> 2) * 128, wn = (wv & 3) * 64;
  const int l15 = lane & 15, k8 = (lane >> 4) * 8;
  const int xorv = (l15 & 7) * 8;  // read-side swizzle (elements)
  const int srow = tid >> 3;
  const int sc8 = ((tid ^ (tid >> 3)) & 7) * 8;  // pre-swizzled source col
  const u16* Ab = A + (size_t)(bm * 256 + srow) * K + sc8;
  const u16* Bb = B + (size_t)(bn * 256 + srow) * K + sc8;

  f32x4 acc[8][4] = {};

#define STAGE(kt, buf)                                                       \
  {                                                                          \
    const int ko = (kt) * 64;                                                \
    _Pragma("unroll") for (int c = 0; c < 4; ++c) {                          \
      gl16(Ab + (size_t)(c * 64) * K + ko, &sA[buf][c * 4096 + wv * 512]);   \
      gl16(Bb + (size_t)(c * 64) * K + ko, &sB[buf][c * 4096 + wv * 512]);   \
    }                                                                        \
  }

  STAGE(0, 0);
  STAGE(1, 1);

  for (int t = 0; t < 8; ++t) {
    const int buf = t & 1;
    if (t == 7)
      vmw0();
    else
      vmw8();  // counted: next tile's 8 loads stay in flight
    __builtin_amdgcn_sched_barrier(0);
    __builtin_amdgcn_s_barrier();  // tile t resident for all waves
#pragma unroll
    for (int mh = 0; mh < 2; ++mh) {
      frag8 af[4][2], bf[2][2][2];
#pragma unroll
      for (int i = 0; i < 4; ++i)
#pragma unroll
        for (int kk = 0; kk < 2; ++kk)
          af[i][kk] = *(const frag8*)&sA[buf][(wm + (mh * 4 + i) * 16 + l15) * 64 +
                                             ((kk * 32 + k8) ^ xorv)];
#pragma unroll
      for (int nh = 0; nh < 2; ++nh)
#pragma unroll
        for (int j = 0; j < 2; ++j)
#pragma unroll
          for (int kk = 0; kk < 2; ++kk)
            bf[nh][j][kk] = *(const frag8*)&sB[buf][(wn + (nh * 2 + j) * 16 + l15) * 64 +
                                                    ((kk * 32 + k8) ^ xorv)];
      lgw0();
      __builtin_amdgcn_sched_barrier(0);
      __builtin_amdgcn_s_setprio(1);
#pragma unroll
      for (int nh = 0; nh < 2; ++nh)
#pragma unroll
        for (int i = 0; i < 4; ++i)
#pragma unroll
          for (int j = 0; j < 2; ++j)
#pragma unroll
            for (int kk = 0; kk < 2; ++kk)
              acc[mh * 4 + i][nh * 2 + j] =
                  MFMA16(af[i][kk], bf[nh][j][kk], acc[mh * 4 + i][nh * 2 + j]);
      __builtin_amdgcn_s_setprio(0);
    }
    __builtin_amdgcn_s_barrier();  // all waves done reading buf -> safe to overwrite
    if (t < 6) STAGE(t + 2, buf);  // issued here: flies under next tile's compute
  }
#undef STAGE

  const int cc = lane & 15, rr = (lane >> 4) * 4;
#pragma unroll
  for (int i = 0; i < 8; ++i)
#pragma unroll
    for (int j = 0; j < 4; ++j) {
      int col = bn * 256 + wn + j * 16 + cc;
      float badd = BIAS ? bias[col] : 0.f;
#pragma unroll
      for (int e = 0; e < 4; ++e) {
        int row = bm * 256 + wm + i * 16 + rr + e;
        C[(size_t)row * N + col] = f2bf(acc[i][j][e] + badd);
      }
    }
}

// ---------------------------------------------------------------- attention (swapped 32x32, barrier-free kb loop)
// One block per (win, head); 4 waves x 64 q-rows. V^T staged once in LDS (one barrier);
// K fragments loaded DIRECTLY global->reg per kb (L2-served, waves fully independent).
__global__ __launch_bounds__(256, 4) void k_attn(const u16* __restrict__ qkv,
                                                 u16* __restrict__ aout) {
  const int g = blockIdx.x;
  const int win = g >> 3, h = g & 7;
  const int tid = threadIdx.x, lane = tid & 63, wv = tid >> 6;
  const int l31 = lane & 31, l5 = lane >> 5;
  __shared__ u16 smem[17408];  // Vt[64][258] = 16512 u16; epilogue scratch 4*4352 = 17408 u16
  u16* VtB = smem;
  const u16* base = qkv + (size_t)win * 256 * 1536;
  const u16* kbase = base + 512 + h * 64;
  const u16* vbase = base + 1024 + h * 64;

  // stage V^T for all 256 keys: thread tid owns key=tid
  {
    const u16* vp = vbase + (size_t)tid * 1536;
#pragma unroll
    for (int c8 = 0; c8 < 64; c8 += 8) {
      short8 v = *(const short8*)(vp + c8);
#pragma unroll
      for (int e2 = 0; e2 < 8; ++e2) VtB[(c8 + e2) * 258 + tid] = (u16)v[e2];
    }
  }
  // Q B-frags: lane holds Q[q=qt*32+l31][c*16 + l5*8 .. +7]
  frag8 qf[2][4];
#pragma unroll
  for (int qt = 0; qt < 2; ++qt)
#pragma unroll
    for (int c = 0; c < 4; ++c)
      qf[qt][c] = *(const frag8*)(base + (size_t)(wv * 64 + qt * 32 + l31) * 1536 + h * 64 +
                                  c * 16 + l5 * 8);
  __syncthreads();  // Vt resident; no more barriers until epilogue

  f32x16 of[2][2] = {};
  float m_run[2] = {-3e38f, -3e38f};
  float l_run[2] = {0.f, 0.f};

  for (int kb = 0; kb < 4; ++kb) {
    // K frags direct from global (wave touches each 128B line exactly once across the 8 loads)
    frag8 kf[2][4];
#pragma unroll
    for (int kr = 0; kr < 2; ++kr)
#pragma unroll
      for (int c = 0; c < 4; ++c)
        kf[kr][c] = *(const frag8*)(kbase + (size_t)(kb * 64 + kr * 32 + l31) * 1536 + c * 16 +
                                    l5 * 8);
#pragma unroll
    for (int qt = 0; qt < 2; ++qt) {
      f32x16 s0 = {}, s1 = {};
#pragma unroll
      for (int c = 0; c < 4; ++c) {
        s0 = MFMA32(kf[0][c], qf[qt][c], s0);
        s1 = MFMA32(kf[1][c], qf[qt][c], s1);
      }
      float tm[16];
#pragma unroll
      for (int r = 0; r < 16; ++r) tm[r] = fmaxf(s0[r], s1[r]);
#pragma unroll
      for (int r = 0; r < 8; ++r) tm[r] = fmaxf(tm[r], tm[r + 8]);
#pragma unroll
      for (int r = 0; r < 4; ++r) tm[r] = fmaxf(tm[r], tm[r + 4]);
      float pm = fmaxf(fmaxf(tm[0], tm[1]), fmaxf(tm[2], tm[3]));
      pm = fmaxf(pm, __shfl_xor(pm, 32));
      if (!__all(pm <= m_run[qt] + 64.f)) {  // defer-max (thr 8 post-scale)
        float mn = fmaxf(m_run[qt], pm);
        float corr = __expf((m_run[qt] - mn) * 0.125f);
        l_run[qt] *= corr;
#pragma unroll
        for (int dt = 0; dt < 2; ++dt)
#pragma unroll
          for (int r = 0; r < 16; ++r) of[qt][dt][r] *= corr;
        m_run[qt] = mn;
      }
      const float mqt = m_run[qt];
      float ls = 0.f;
#pragma unroll
      for (int kt = 0; kt < 2; ++kt) {
        const f32x16 sv = kt ? s1 : s0;
        float p[16];
#pragma unroll
        for (int r = 0; r < 16; ++r) p[r] = __expf((sv[r] - mqt) * 0.125f);
        float e0 = (p[0] + p[1]) + (p[2] + p[3]);
        float e1 = (p[4] + p[5]) + (p[6] + p[7]);
        float e2 = (p[8] + p[9]) + (p[10] + p[11]);
        float e3 = (p[12] + p[13]) + (p[14] + p[15]);
        ls += (e0 + e1) + (e2 + e3);
#pragma unroll
        for (int cc = 0; cc < 2; ++cc) {
          const int bx = cc * 8;
          unsigned a0 = cvtpk_bf16(p[bx + 0], p[bx + 1]);
          unsigned a1 = cvtpk_bf16(p[bx + 2], p[bx + 3]);
          unsigned b0 = cvtpk_bf16(p[bx + 4], p[bx + 5]);
          unsigned b1 = cvtpk_bf16(p[bx + 6], p[bx + 7]);
          // cross-half exchange: D_new={D.lo,S.lo}, S_new={D.hi,S.hi}
          asm("v_permlane32_swap_b32 %0, %1" : "+v"(a0), "+v"(b0));
          asm("v_permlane32_swap_b32 %0, %1" : "+v"(a1), "+v"(b1));
          uint4 fu;
          fu.x = a0;
          fu.y = a1;
          fu.z = b0;
          fu.w = b1;
          frag8 pb = __builtin_bit_cast(frag8, fu);
#pragma unroll
          for (int dt = 0; dt < 2; ++dt) {
            frag8 va = *(const frag8*)&VtB[(dt * 32 + l31) * 258 + kb * 64 + kt * 32 + cc * 16 +
                                           l5 * 8];
            of[qt][dt] = MFMA32(va, pb, of[qt][dt]);
          }
        }
      }
      l_run[qt] += ls;
    }
  }

  float inv[2];
#pragma unroll
  for (int qt = 0; qt < 2; ++qt) {
    float lt = l_run[qt] + __shfl_xor(l_run[qt], 32);
    inv[qt] = 1.0f / lt;
  }
  u16* sc = smem + wv * 4352;  // per-wave [64][68] scratch (reuses Vt LDS)
  __syncthreads();             // all waves done with Vt
#pragma unroll
  for (int qt = 0; qt < 2; ++qt)
#pragma unroll
    for (int dt = 0; dt < 2; ++dt)
#pragma unroll
      for (int j = 0; j < 4; ++j) {
        unsigned w0 = cvtpk_bf16(of[qt][dt][4 * j + 0] * inv[qt], of[qt][dt][4 * j + 1] * inv[qt]);
        unsigned w1 = cvtpk_bf16(of[qt][dt][4 * j + 2] * inv[qt], of[qt][dt][4 * j + 3] * inv[qt]);
        *(uint2*)&sc[(qt * 32 + l31) * 68 + dt * 32 + 8 * j + 4 * l5] = make_uint2(w0, w1);
      }
  asm volatile("" ::: "memory");
#pragma unroll
  for (int rep = 0; rep < 8; ++rep) {
    int row = rep * 8 + (lane >> 3);
    uint2 lo = *(const uint2*)&sc[row * 68 + (lane & 7) * 8];
    uint2 hi = *(const uint2*)&sc[row * 68 + (lane & 7) * 8 + 4];
    *(int4*)&aout[(size_t)(win * 256 + wv * 64 + row) * 512 + h * 64 + (lane & 7) * 8] =
        make_int4((int)lo.x, (int)lo.y, (int)hi.x, (int)hi.y);
  }
}

// ---------------------------------------------------------------- finalize
__global__ void k_final(const float* __restrict__ x, const u16* __restrict__ proj,
                        const int* __restrict__ kept, const float* __restrict__ mult,
                        float* __restrict__ out) {
  const size_t idx = (size_t)blockIdx.x * 256 + threadIdx.x;
  const int dci = (int)(idx & 31);
  const int pix = (int)((idx >> 5) & 16383);
  const int b = (int)(idx >> 19);
  const int y = pix >> 7, xc = pix & 127;
  float acc[16];
#pragma unroll
  for (int e = 0; e < 16; ++e) acc[e] = 0.f;
  float c = 0.f;
  const int wyh = y >> 3, wxh = xc >> 3;
#pragma unroll
  for (int a = 0; a < 2; ++a) {
    int wy = wyh - 1 + a;
    if (wy < 0 || wy > 14) continue;
#pragma unroll
    for (int bb = 0; bb < 2; ++bb) {
      int wx = wxh - 1 + bb;
      if (wx < 0 || wx > 14) continue;
      int w = wy * 15 + wx;
      int slot = kept[b * 225 + w];
      if (slot < 0) continue;
      float ml = mult[b * 225 + w];
      c += ml;
      const u16* pr = proj +
                      ((size_t)((b * 44 + slot) * 256 + (y - wy * 8) * 16 + (xc - wx * 8))) * 512 +
                      (size_t)dci * 16;
      short8 v0 = *(const short8*)pr;
      short8 v1 = *(const short8*)(pr + 8);
#pragma unroll
      for (int e = 0; e < 8; ++e) acc[e] += ml * bf2f((u16)v0[e]);
#pragma unroll
      for (int e = 0; e < 8; ++e) acc[8 + e] += ml * bf2f((u16)v1[e]);
    }
  }
  const float inv = 1.f / (c + 1e-10f);
  const size_t off = ((size_t)(b * 16384 + pix)) * 512 + (size_t)dci * 16;
  const float4* xp = (const float4*)(x + off);
  float4* op = (float4*)(out + off);
#pragma unroll
  for (int q4 = 0; q4 < 4; ++q4) {
    float4 xv = xp[q4];
    float4 ov;
    ov.x = xv.x + acc[q4 * 4 + 0] * inv;
    ov.y = xv.y + acc[q4 * 4 + 1] * inv;
    ov.z = xv.z + acc[q4 * 4 + 2] * inv;
    ov.w = xv.w + acc[q4 * 4 + 3] * inv;
    op[q4] = ov;
  }
}

// ---------------------------------------------------------------- launch
extern "C" void kernel_launch(void* const* d_in, const int* in_sizes, int n_in, void* d_out,
                              int out_size, void* d_ws, size_t ws_size, hipStream_t stream) {
  const float* x = (const float*)d_in[0];
  const float* prob = (const float*)d_in[1];
  const float* wfix = (const float*)d_in[2];
  const float* Wq = (const float*)d_in[3];
  const float* Wo = (const float*)d_in[4];
  const float* bo = (const float*)d_in[5];
  float* out = (float*)d_out;
  char* ws = (char*)d_ws;

  float* scores = (float*)(ws + 0);
  int* sel = (int*)(ws + 8192);
  int* kept = (int*)(ws + 16384);
  float* mult = (float*)(ws + 24576);
  u16* wqb = (u16*)(ws + 32768);
  u16* wob = (u16*)(ws + 32768 + 1572864);
  u16* xi = (u16*)(ws + 4194304);
  u16* qkv = (u16*)(ws + 4194304 + 92274688);
  u16* aout = xi;
  u16* proj = qkv;

  k_score<<<8, 256, 0, stream>>>(prob, wfix, scores);
  k_nms<<<8, 256, 0, stream>>>(scores, sel, kept, mult);
  k_castw<<<4096, 256, 0, stream>>>(Wq, Wo, wqb, wob);
  k_gather<<<22528, 256, 0, stream>>>(x, sel, xi);
  k_gemm256<0><<<2112, 512, 0, stream>>>(xi, wqb, qkv, nullptr, 90112, 1536, 512, 6);
  k_attn<<<2816, 256, 0, stream>>>(qkv, aout);
  k_gemm256<1><<<704, 512, 0, stream>>>(aout, wob, proj, bo, 90112, 512, 512, 2);
  k_final<<<16384, 256, 0, stream>>>(x, proj, kept, mult, out);
}

// Round 9
// 733.070 us; speedup vs baseline: 1.5250x; 1.5250x over previous
//
#include <hip/hip_runtime.h>
#include <type_traits>
#include <utility>

typedef unsigned short u16;
typedef __attribute__((ext_vector_type(8))) short short8;
typedef __attribute__((ext_vector_type(8))) __bf16 bf16v8;
typedef __attribute__((ext_vector_type(4))) float f32x4;
typedef __attribute__((ext_vector_type(16))) float f32x16;

template <typename T, typename = void> struct mfma_ok : std::false_type {};
template <typename T>
struct mfma_ok<T, std::void_t<decltype(__builtin_amdgcn_mfma_f32_16x16x32_bf16(
    std::declval<T>(), std::declval<T>(), std::declval<f32x4>(), 0, 0, 0))>>
    : std::true_type {};
using frag8 = std::conditional_t<mfma_ok<bf16v8>::value, bf16v8, short8>;

#define MFMA16(a, b, c) __builtin_amdgcn_mfma_f32_16x16x32_bf16((a), (b), (c), 0, 0, 0)
#define MFMA32(a, b, c) __builtin_amdgcn_mfma_f32_32x32x16_bf16((a), (b), (c), 0, 0, 0)

__device__ __forceinline__ float bf2f(u16 u) {
  unsigned v = ((unsigned)u) << 16;
  return __builtin_bit_cast(float, v);
}
__device__ __forceinline__ u16 f2bf(float f) {
  unsigned u = __builtin_bit_cast(unsigned, f);
  u = (u + 0x7fffu + ((u >> 16) & 1u)) >> 16;
  return (u16)u;
}
__device__ __forceinline__ unsigned cvtpk_bf16(float lo, float hi) {
  unsigned r;
  asm("v_cvt_pk_bf16_f32 %0, %1, %2" : "=v"(r) : "v"(lo), "v"(hi));
  return r;
}
// async global->LDS, 16B per lane; lds ptr must be wave-uniform base (+lane*16 implicit)
__device__ __forceinline__ void gl16(const u16* g, u16* l) {
  __builtin_amdgcn_global_load_lds((__attribute__((address_space(1))) void*)(g),
                                   (__attribute__((address_space(3))) void*)(l), 16, 0, 0);
}
__device__ __forceinline__ void vmw8() { asm volatile("s_waitcnt vmcnt(8)" ::: "memory"); }
__device__ __forceinline__ void vmw0() { asm volatile("s_waitcnt vmcnt(0)" ::: "memory"); }
__device__ __forceinline__ void lgw0() { asm volatile("s_waitcnt lgkmcnt(0)" ::: "memory"); }

// ---------------------------------------------------------------- score
__global__ void k_score(const float* __restrict__ prob, const float* __restrict__ wfix,
                        float* __restrict__ scores) {
  const int b = blockIdx.x, tid = threadIdx.x;
  __shared__ float ent[64 * 64];
  __shared__ float wf[64];
  if (tid < 64) wf[tid] = wfix[tid];
  const float* pb = prob + (size_t)b * 4 * 4096;
  for (int p = tid; p < 4096; p += 256) {
    float e = 0.f;
#pragma unroll
    for (int ch = 0; ch < 4; ++ch) {
      float v = pb[ch * 4096 + p];
      e -= v * log2f(v + 1e-10f);
    }
    ent[p] = e;
  }
  __syncthreads();
  if (tid < 225) {
    int wy = tid / 15, wx = tid % 15;
    float s = 0.f;
    for (int a = 0; a < 8; ++a)
      for (int c = 0; c < 8; ++c)
        s += ent[(wy * 4 + a) * 64 + wx * 4 + c] * wf[a * 8 + c];
    scores[b * 225 + tid] = s * (1.0f / 64.0f);
  }
}

// ---------------------------------------------------------------- nms
__device__ __forceinline__ float iou_pair(int wa, int wb) {
  float x1a = (float)((wa % 15) * 8), y1a = (float)((wa / 15) * 8);
  float x1b = (float)((wb % 15) * 8), y1b = (float)((wb / 15) * 8);
  float iw = fminf(x1a, x1b) + 15.f - fmaxf(x1a, x1b);
  float ih = fminf(y1a, y1b) + 15.f - fmaxf(y1a, y1b);
  iw = fmaxf(iw, 0.f);
  ih = fmaxf(ih, 0.f);
  float inter = iw * ih;
  return inter / (450.f - inter);
}

__global__ void k_nms(const float* __restrict__ scores, int* __restrict__ sel,
                      int* __restrict__ kept, float* __restrict__ mult) {
  const int b = blockIdx.x, t = threadIdx.x;
  __shared__ float s[225];
  __shared__ int order[225];
  __shared__ unsigned char supp[225];
  __shared__ int idx44[44];
  __shared__ int ks[225];
  __shared__ float ml[225];
  if (t < 225) s[t] = scores[b * 225 + t];
  __syncthreads();
  if (t < 225) {
    float st = s[t];
    int r = 0;
    for (int j = 0; j < 225; ++j) {
      float sj = s[j];
      r += (sj > st) || (sj == st && j < t);
    }
    order[r] = t;
    supp[t] = 0;
    ks[t] = -1;
    ml[t] = 0.f;
  }
  __syncthreads();
  for (int i = 0; i < 224; ++i) {
    if (t > i && t < 225 && !supp[i]) {
      if (iou_pair(order[i], order[t]) > 0.2f) supp[t] = 1;
    }
    __syncthreads();
  }
  if (t == 0) {
    int k = 0;
    for (int i = 0; i < 225 && k < 44; ++i)
      if (!supp[i]) idx44[k++] = order[i];
    while (k < 44) idx44[k++] = order[224];
    for (int k2 = 0; k2 < 44; ++k2) {
      int w = idx44[k2];
      if (ks[w] < 0) ks[w] = k2;
      ml[w] += 1.f;
    }
  }
  __syncthreads();
  if (t < 225) {
    kept[b * 225 + t] = ks[t];
    mult[b * 225 + t] = ml[t];
  }
  if (t < 44) sel[b * 44 + t] = idx44[t];
}

// ---------------------------------------------------------------- weight cast
__global__ void k_castw(const float* __restrict__ Wq, const float* __restrict__ Wo,
                        u16* __restrict__ wqb, u16* __restrict__ wob) {
  int idx = blockIdx.x * 256 + threadIdx.x;
  if (idx < 786432) wqb[idx] = f2bf(Wq[idx]);
  int i2 = idx - 786432;
  if (i2 >= 0 && i2 < 262144) wob[i2] = f2bf(Wo[i2]);
}

// ---------------------------------------------------------------- gather + bilinear (direct 4-tap)
__global__ __launch_bounds__(256) void k_gather(const float* __restrict__ x,
                                                const int* __restrict__ sel,
                                                u16* __restrict__ xi) {
  const size_t idx = (size_t)blockIdx.x * 256 + threadIdx.x;
  const int dc = (int)(idx & 63);
  const int pq = (int)((idx >> 6) & 255);
  const int g = (int)(idx >> 14);
  const int b = g / 44;
  const int w = sel[g];
  const int sy = (w / 15) * 8, sx = (w % 15) * 8;
  const int p = pq >> 4, q = pq & 15;
  float rp = ((float)p + 0.5f) * 0.9375f;
  int i0 = (int)rp;
  float fp = rp - (float)i0;
  float rq = ((float)q + 0.5f) * 0.9375f;
  int j0 = (int)rq;
  float fq = rq - (float)j0;
  const float w00 = (1.f - fp) * (1.f - fq), w01 = (1.f - fp) * fq;
  const float w10 = fp * (1.f - fq), w11 = fp * fq;
  const float* xb = x + ((size_t)b * 16384 + (size_t)(sy + i0) * 128 + sx + j0) * 512 + dc * 8;
  const float4* t00 = (const float4*)xb;
  const float4* t01 = (const float4*)(xb + 512);
  const float4* t10 = (const float4*)(xb + 512 * 128);
  const float4* t11 = (const float4*)(xb + 512 * 129);
  float acc[8];
#pragma unroll
  for (int h = 0; h < 2; ++h) {
    float4 a = t00[h], bb = t01[h], c = t10[h], d = t11[h];
    acc[h * 4 + 0] = w00 * a.x + w01 * bb.x + w10 * c.x + w11 * d.x;
    acc[h * 4 + 1] = w00 * a.y + w01 * bb.y + w10 * c.y + w11 * d.y;
    acc[h * 4 + 2] = w00 * a.z + w01 * bb.z + w10 * c.z + w11 * d.z;
    acc[h * 4 + 3] = w00 * a.w + w01 * bb.w + w10 * c.w + w11 * d.w;
  }
  short8 o;
#pragma unroll
  for (int e = 0; e < 8; ++e) o[e] = (short)f2bf(acc[e]);
  *(short8*)&xi[((size_t)g * 256 + pq) * 512 + dc * 8] = o;
}

// ---------------------------------------------------------------- GEMM 256x256, BK=64, 8 waves
// Counted-vmcnt dbuf + T2 XOR swizzle + per-mh fragment hoist. In-tile lgkm drains removed:
// the compiler inserts fine-grained lgkmcnt between ds_read and MFMA (m97/m141 evidence),
// so reads of phase mh=1 overlap MFMAs of mh=0. lgkmcnt(0) kept only before the
// buffer-release barrier (correctness: DMA must not overwrite LDS still being read).
template <int BIAS>
__global__ __launch_bounds__(512, 2) void k_gemm256(const u16* __restrict__ A,
                                                    const u16* __restrict__ B, u16* __restrict__ C,
                                                    const float* __restrict__ bias, int M, int N,
                                                    int K, int nbn) {
  __shared__ u16 sA[2][256 * 64];
  __shared__ u16 sB[2][256 * 64];
  const int tid = threadIdx.x, lane = tid & 63, wv = tid >> 6;
  const int f = blockIdx.x;
  const int q8 = gridDim.x >> 3;
  const int wg = (f & 7) * q8 + (f >> 3);
  const int bm = wg / nbn, bn = wg % nbn;
  const int wm = (wv >> 2) * 128, wn = (wv & 3) * 64;
  const int l15 = lane & 15, k8 = (lane >> 4) * 8;
  const int xorv = (l15 & 7) * 8;  // read-side swizzle (elements)
  const int srow = tid >> 3;
  const int sc8 = ((tid ^ (tid >> 3)) & 7) * 8;  // pre-swizzled source col
  const u16* Ab = A + (size_t)(bm * 256 + srow) * K + sc8;
  const u16* Bb = B + (size_t)(bn * 256 + srow) * K + sc8;

  f32x4 acc[8][4] = {};

#define STAGE(kt, buf)                                                       \
  {                                                                          \
    const int ko = (kt) * 64;                                                \
    _Pragma("unroll") for (int c = 0; c < 4; ++c) {                          \
      gl16(Ab + (size_t)(c * 64) * K + ko, &sA[buf][c * 4096 + wv * 512]);   \
      gl16(Bb + (size_t)(c * 64) * K + ko, &sB[buf][c * 4096 + wv * 512]);   \
    }                                                                        \
  }

  STAGE(0, 0);
  STAGE(1, 1);

  for (int t = 0; t < 8; ++t) {
    const int buf = t & 1;
    if (t == 7)
      vmw0();
    else
      vmw8();  // counted: next tile's 8 loads stay in flight
    __builtin_amdgcn_sched_barrier(0);
    __builtin_amdgcn_s_barrier();  // tile t resident for all waves
#pragma unroll
    for (int mh = 0; mh < 2; ++mh) {
      frag8 af[4][2], bf[2][2][2];
#pragma unroll
      for (int i = 0; i < 4; ++i)
#pragma unroll
        for (int kk = 0; kk < 2; ++kk)
          af[i][kk] = *(const frag8*)&sA[buf][(wm + (mh * 4 + i) * 16 + l15) * 64 +
                                             ((kk * 32 + k8) ^ xorv)];
#pragma unroll
      for (int nh = 0; nh < 2; ++nh)
#pragma unroll
        for (int j = 0; j < 2; ++j)
#pragma unroll
          for (int kk = 0; kk < 2; ++kk)
            bf[nh][j][kk] = *(const frag8*)&sB[buf][(wn + (nh * 2 + j) * 16 + l15) * 64 +
                                                    ((kk * 32 + k8) ^ xorv)];
      __builtin_amdgcn_s_setprio(1);
#pragma unroll
      for (int nh = 0; nh < 2; ++nh)
#pragma unroll
        for (int i = 0; i < 4; ++i)
#pragma unroll
          for (int j = 0; j < 2; ++j)
#pragma unroll
            for (int kk = 0; kk < 2; ++kk)
              acc[mh * 4 + i][nh * 2 + j] =
                  MFMA16(af[i][kk], bf[nh][j][kk], acc[mh * 4 + i][nh * 2 + j]);
      __builtin_amdgcn_s_setprio(0);
    }
    lgw0();  // this wave's ds_reads fully retired before buf can be overwritten
    __builtin_amdgcn_sched_barrier(0);
    __builtin_amdgcn_s_barrier();  // all waves done reading buf
    if (t < 6) STAGE(t + 2, buf);  // issued here: flies under next tile's compute
  }
#undef STAGE

  const int cc = lane & 15, rr = (lane >> 4) * 4;
#pragma unroll
  for (int i = 0; i < 8; ++i)
#pragma unroll
    for (int j = 0; j < 4; ++j) {
      int col = bn * 256 + wn + j * 16 + cc;
      float badd = BIAS ? bias[col] : 0.f;
#pragma unroll
      for (int e = 0; e < 4; ++e) {
        int row = bm * 256 + wm + i * 16 + rr + e;
        C[(size_t)row * N + col] = f2bf(acc[i][j][e] + badd);
      }
    }
}

// ---------------------------------------------------------------- attention (swapped 32x32)
// One block per (win, head); 4 waves x 64 q-rows. K AND V double-buffered per 64-key block
// (LDS 35.3 KB). P^T B-frags built in-register via cvt_pk + permlane32_swap. (round-7 version)
__global__ __launch_bounds__(256, 3) void k_attn(const u16* __restrict__ qkv,
                                                 u16* __restrict__ aout) {
  const int g = blockIdx.x;
  const int win = g >> 3, h = g & 7;
  const int tid = threadIdx.x, lane = tid & 63, wv = tid >> 6;
  const int l31 = lane & 31, l5 = lane >> 5;
  __shared__ u16 smem[17664];  // Kb[2][64][68] (8704 u16) | Vt[2][64][70] (8960 u16)
  u16* KbB = smem;
  u16* VtB = smem + 8704;
  const u16* base = qkv + (size_t)win * 256 * 1536;
  const u16* kbase = base + 512 + h * 64;
  const u16* vbase = base + 1024 + h * 64;
  const int prow = tid >> 2, pc16 = (tid & 3) * 16;

  // Q B-frags first (longest-latency dependency)
  frag8 qf[2][4];
#pragma unroll
  for (int qt = 0; qt < 2; ++qt)
#pragma unroll
    for (int c = 0; c < 4; ++c)
      qf[qt][c] = *(const frag8*)(base + (size_t)(wv * 64 + qt * 32 + l31) * 1536 + h * 64 +
                                  c * 16 + l5 * 8);
  // K block 0 + V block 0 (thread: key=prow, d-range pc16..pc16+15)
  {
    const u16* kp = kbase + (size_t)prow * 1536 + pc16;
    short8 ka = *(const short8*)kp;
    short8 kb2 = *(const short8*)(kp + 8);
    const u16* vp = vbase + (size_t)prow * 1536 + pc16;
    short8 va = *(const short8*)vp;
    short8 vb2 = *(const short8*)(vp + 8);
    *(short8*)&KbB[prow * 68 + pc16] = ka;
    *(short8*)&KbB[prow * 68 + pc16 + 8] = kb2;
#pragma unroll
    for (int e = 0; e < 8; ++e) {
      VtB[(pc16 + e) * 70 + prow] = (u16)va[e];
      VtB[(pc16 + 8 + e) * 70 + prow] = (u16)vb2[e];
    }
  }
  __syncthreads();

  f32x16 of[2][2] = {};
  float m_run[2] = {-3e38f, -3e38f};
  float l_run[2] = {0.f, 0.f};

  int cur = 0;
  for (int kb = 0; kb < 4; ++kb) {
    short8 pk0 = {}, pk1 = {}, pv0 = {}, pv1 = {};
    if (kb < 3) {
      const u16* kp = kbase + (size_t)((kb + 1) * 64 + prow) * 1536 + pc16;
      pk0 = *(const short8*)kp;
      pk1 = *(const short8*)(kp + 8);
      const u16* vp = vbase + (size_t)((kb + 1) * 64 + prow) * 1536 + pc16;
      pv0 = *(const short8*)vp;
      pv1 = *(const short8*)(vp + 8);
    }
#pragma unroll
    for (int qt = 0; qt < 2; ++qt) {
      f32x16 s0 = {}, s1 = {};
#pragma unroll
      for (int c = 0; c < 4; ++c) {
        frag8 kf0 = *(const frag8*)&KbB[cur * 4352 + l31 * 68 + c * 16 + l5 * 8];
        frag8 kf1 = *(const frag8*)&KbB[cur * 4352 + (32 + l31) * 68 + c * 16 + l5 * 8];
        s0 = MFMA32(kf0, qf[qt][c], s0);
        s1 = MFMA32(kf1, qf[qt][c], s1);
      }
      float tm[16];
#pragma unroll
      for (int r = 0; r < 16; ++r) tm[r] = fmaxf(s0[r], s1[r]);
#pragma unroll
      for (int r = 0; r < 8; ++r) tm[r] = fmaxf(tm[r], tm[r + 8]);
#pragma unroll
      for (int r = 0; r < 4; ++r) tm[r] = fmaxf(tm[r], tm[r + 4]);
      float pm = fmaxf(fmaxf(tm[0], tm[1]), fmaxf(tm[2], tm[3]));
      pm = fmaxf(pm, __shfl_xor(pm, 32));
      if (!__all(pm <= m_run[qt] + 64.f)) {  // defer-max (thr 8 post-scale)
        float mn = fmaxf(m_run[qt], pm);
        float corr = __expf((m_run[qt] - mn) * 0.125f);
        l_run[qt] *= corr;
#pragma unroll
        for (int dt = 0; dt < 2; ++dt)
#pragma unroll
          for (int r = 0; r < 16; ++r) of[qt][dt][r] *= corr;
        m_run[qt] = mn;
      }
      const float mqt = m_run[qt];
      float ls = 0.f;
#pragma unroll
      for (int kt = 0; kt < 2; ++kt) {
        const f32x16 sv = kt ? s1 : s0;
        float p[16];
#pragma unroll
        for (int r = 0; r < 16; ++r) p[r] = __expf((sv[r] - mqt) * 0.125f);
        float e0 = (p[0] + p[1]) + (p[2] + p[3]);
        float e1 = (p[4] + p[5]) + (p[6] + p[7]);
        float e2 = (p[8] + p[9]) + (p[10] + p[11]);
        float e3 = (p[12] + p[13]) + (p[14] + p[15]);
        ls += (e0 + e1) + (e2 + e3);
#pragma unroll
        for (int cc = 0; cc < 2; ++cc) {
          const int bx = cc * 8;
          unsigned a0 = cvtpk_bf16(p[bx + 0], p[bx + 1]);
          unsigned a1 = cvtpk_bf16(p[bx + 2], p[bx + 3]);
          unsigned b0 = cvtpk_bf16(p[bx + 4], p[bx + 5]);
          unsigned b1 = cvtpk_bf16(p[bx + 6], p[bx + 7]);
          // cross-half exchange: D_new={D.lo,S.lo}, S_new={D.hi,S.hi}
          asm("v_permlane32_swap_b32 %0, %1" : "+v"(a0), "+v"(b0));
          asm("v_permlane32_swap_b32 %0, %1" : "+v"(a1), "+v"(b1));
          uint4 fu;
          fu.x = a0;
          fu.y = a1;
          fu.z = b0;
          fu.w = b1;
          frag8 pb = __builtin_bit_cast(frag8, fu);
#pragma unroll
          for (int dt = 0; dt < 2; ++dt) {
            frag8 va = *(const frag8*)&VtB[cur * 4480 + (dt * 32 + l31) * 70 + kt * 32 + cc * 16 +
                                           l5 * 8];
            of[qt][dt] = MFMA32(va, pb, of[qt][dt]);
          }
        }
      }
      l_run[qt] += ls;
    }
    if (kb < 3) {
      *(short8*)&KbB[(cur ^ 1) * 4352 + prow * 68 + pc16] = pk0;
      *(short8*)&KbB[(cur ^ 1) * 4352 + prow * 68 + pc16 + 8] = pk1;
      u16* vd = &VtB[(cur ^ 1) * 4480 + prow];
#pragma unroll
      for (int e = 0; e < 8; ++e) {
        vd[(pc16 + e) * 70] = (u16)pv0[e];
        vd[(pc16 + 8 + e) * 70] = (u16)pv1[e];
      }
    }
    __syncthreads();
    cur ^= 1;
  }

  float inv[2];
#pragma unroll
  for (int qt = 0; qt < 2; ++qt) {
    float lt = l_run[qt] + __shfl_xor(l_run[qt], 32);
    inv[qt] = 1.0f / lt;
  }
  u16* sc = smem + wv * 4352;  // per-wave [64][68] scratch (reuses K/V LDS)
  __syncthreads();
#pragma unroll
  for (int qt = 0; qt < 2; ++qt)
#pragma unroll
    for (int dt = 0; dt < 2; ++dt)
#pragma unroll
      for (int j = 0; j < 4; ++j) {
        unsigned w0 = cvtpk_bf16(of[qt][dt][4 * j + 0] * inv[qt], of[qt][dt][4 * j + 1] * inv[qt]);
        unsigned w1 = cvtpk_bf16(of[qt][dt][4 * j + 2] * inv[qt], of[qt][dt][4 * j + 3] * inv[qt]);
        *(uint2*)&sc[(qt * 32 + l31) * 68 + dt * 32 + 8 * j + 4 * l5] = make_uint2(w0, w1);
      }
  asm volatile("" ::: "memory");
#pragma unroll
  for (int rep = 0; rep < 8; ++rep) {
    int row = rep * 8 + (lane >> 3);
    uint2 lo = *(const uint2*)&sc[row * 68 + (lane & 7) * 8];
    uint2 hi = *(const uint2*)&sc[row * 68 + (lane & 7) * 8 + 4];
    *(int4*)&aout[(size_t)(win * 256 + wv * 64 + row) * 512 + h * 64 + (lane & 7) * 8] =
        make_int4((int)lo.x, (int)lo.y, (int)hi.x, (int)hi.y);
  }
}

// ---------------------------------------------------------------- finalize
__global__ void k_final(const float* __restrict__ x, const u16* __restrict__ proj,
                        const int* __restrict__ kept, const float* __restrict__ mult,
                        float* __restrict__ out) {
  const size_t idx = (size_t)blockIdx.x * 256 + threadIdx.x;
  const int dci = (int)(idx & 31);
  const int pix = (int)((idx >> 5) & 16383);
  const int b = (int)(idx >> 19);
  const int y = pix >> 7, xc = pix & 127;
  float acc[16];
#pragma unroll
  for (int e = 0; e < 16; ++e) acc[e] = 0.f;
  float c = 0.f;
  const int wyh = y >> 3, wxh = xc >> 3;
#pragma unroll
  for (int a = 0; a < 2; ++a) {
    int wy = wyh - 1 + a;
    if (wy < 0 || wy > 14) continue;
#pragma unroll
    for (int bb = 0; bb < 2; ++bb) {
      int wx = wxh - 1 + bb;
      if (wx < 0 || wx > 14) continue;
      int w = wy * 15 + wx;
      int slot = kept[b * 225 + w];
      if (slot < 0) continue;
      float ml = mult[b * 225 + w];
      c += ml;
      const u16* pr = proj +
                      ((size_t)((b * 44 + slot) * 256 + (y - wy * 8) * 16 + (xc - wx * 8))) * 512 +
                      (size_t)dci * 16;
      short8 v0 = *(const short8*)pr;
      short8 v1 = *(const short8*)(pr + 8);
#pragma unroll
      for (int e = 0; e < 8; ++e) acc[e] += ml * bf2f((u16)v0[e]);
#pragma unroll
      for (int e = 0; e < 8; ++e) acc[8 + e] += ml * bf2f((u16)v1[e]);
    }
  }
  const float inv = 1.f / (c + 1e-10f);
  const size_t off = ((size_t)(b * 16384 + pix)) * 512 + (size_t)dci * 16;
  const float4* xp = (const float4*)(x + off);
  float4* op = (float4*)(out + off);
#pragma unroll
  for (int q4 = 0; q4 < 4; ++q4) {
    float4 xv = xp[q4];
    float4 ov;
    ov.x = xv.x + acc[q4 * 4 + 0] * inv;
    ov.y = xv.y + acc[q4 * 4 + 1] * inv;
    ov.z = xv.z + acc[q4 * 4 + 2] * inv;
    ov.w = xv.w + acc[q4 * 4 + 3] * inv;
    op[q4] = ov;
  }
}

// ---------------------------------------------------------------- launch
extern "C" void kernel_launch(void* const* d_in, const int* in_sizes, int n_in, void* d_out,
                              int out_size, void* d_ws, size_t ws_size, hipStream_t stream) {
  const float* x = (const float*)d_in[0];
  const float* prob = (const float*)d_in[1];
  const float* wfix = (const float*)d_in[2];
  const float* Wq = (const float*)d_in[3];
  const float* Wo = (const float*)d_in[4];
  const float* bo = (const float*)d_in[5];
  float* out = (float*)d_out;
  char* ws = (char*)d_ws;

  float* scores = (float*)(ws + 0);
  int* sel = (int*)(ws + 8192);
  int* kept = (int*)(ws + 16384);
  float* mult = (float*)(ws + 24576);
  u16* wqb = (u16*)(ws + 32768);
  u16* wob = (u16*)(ws + 32768 + 1572864);
  u16* xi = (u16*)(ws + 4194304);
  u16* qkv = (u16*)(ws + 4194304 + 92274688);
  u16* aout = xi;
  u16* proj = qkv;

  k_score<<<8, 256, 0, stream>>>(prob, wfix, scores);
  k_nms<<<8, 256, 0, stream>>>(scores, sel, kept, mult);
  k_castw<<<4096, 256, 0, stream>>>(Wq, Wo, wqb, wob);
  k_gather<<<22528, 256, 0, stream>>>(x, sel, xi);
  k_gemm256<0><<<2112, 512, 0, stream>>>(xi, wqb, qkv, nullptr, 90112, 1536, 512, 6);
  k_attn<<<2816, 256, 0, stream>>>(qkv, aout);
  k_gemm256<1><<<704, 512, 0, stream>>>(aout, wob, proj, bo, 90112, 512, 512, 2);
  k_final<<<16384, 256, 0, stream>>>(x, proj, kept, mult, out);
}